// Round 10
// baseline (1701.901 us; speedup 1.0000x reference)
//
#include <hip/hip_runtime.h>
#include <hip/hip_bf16.h>
#include <cstddef>

// Problem constants
#define BB 8
#define LL 5
#define NN 4096
#define NANCH 64
#define NPTS 4160      // NN + NANCH
#define MM 260         // NPTS / 16
#define NFRAME 3
#define SSEQ 780       // NFRAME * MM
#define DIMC 512
#define NHEAD 8
#define DHEAD 64
#define MLPD 1024
#define OUTD 1088
#define NROWS 6240     // BB * SSEQ
#define VPITCH 784     // vT key pitch (780 padded to 16B-aligned rows)
#define WBUFSZ 2097152 // ushorts per weight buffer (qkv|proj|ff1|ff2)

typedef __attribute__((ext_vector_type(8))) short s16x8;
typedef __attribute__((ext_vector_type(4))) float fx4;
typedef unsigned short ushort_t;
typedef unsigned int uint_t;
typedef unsigned long long u64_t;

// exact (non-contracted) squared distance, matching numpy fp32 op order
__device__ __forceinline__ float sqdist_rn(float x1, float y1, float z1,
                                           float x2, float y2, float z2) {
    float dx = __fsub_rn(x1, x2);
    float dy = __fsub_rn(y1, y2);
    float dz = __fsub_rn(z1, z2);
    return __fadd_rn(__fadd_rn(__fmul_rn(dx, dx), __fmul_rn(dy, dy)), __fmul_rn(dz, dz));
}

__device__ __forceinline__ float gelu_exact(float v) {
    return 0.5f * v * (1.0f + erff(v * 0.70710678118654752440f));
}

// round-to-nearest bf16
__device__ __forceinline__ uint_t bf16rn(float f) {
    uint_t u = __float_as_uint(f);
    return (u + 0x7FFFu + ((u >> 16) & 1u)) >> 16;
}
// split fp32 into bf16 hi + bf16 lo (residual)
__device__ __forceinline__ void split2(float f, ushort_t& h, ushort_t& l) {
    uint_t hb = bf16rn(f);
    h = (ushort_t)hb;
    float fh = __uint_as_float(hb << 16);
    l = (ushort_t)bf16rn(f - fh);
}

// async global->LDS (16B per lane; dest = wave-uniform base + lane*16)
typedef __attribute__((address_space(3))) unsigned int as3u;
typedef const __attribute__((address_space(1))) unsigned int as1u;
__device__ __forceinline__ void gload16(const ushort_t* g, ushort_t* l) {
    __builtin_amdgcn_global_load_lds((as1u*)g, (as3u*)l, 16, 0, 0);
}

// ---- DPP wave64 reductions. ctrl must be an immediate -> template param.
template <int CTRL>
__device__ __forceinline__ int dpp_mov(int v) {
    return __builtin_amdgcn_update_dpp(0, v, CTRL, 0xF, 0xF, true);
}
#define DPP_STEP_F(op, v, ctrl) v = op(v, __int_as_float(dpp_mov<ctrl>(__float_as_int(v))))
__device__ __forceinline__ float wave_max_bcast(float v) {
    DPP_STEP_F(fmaxf, v, 0x111); DPP_STEP_F(fmaxf, v, 0x112);
    DPP_STEP_F(fmaxf, v, 0x114); DPP_STEP_F(fmaxf, v, 0x118);
    DPP_STEP_F(fmaxf, v, 0x142); DPP_STEP_F(fmaxf, v, 0x143);
    return __int_as_float(__builtin_amdgcn_readlane(__float_as_int(v), 63));
}
__device__ __forceinline__ float faddf(float a, float b) { return a + b; }
__device__ __forceinline__ float wave_sum_bcast(float v) {
    DPP_STEP_F(faddf, v, 0x111); DPP_STEP_F(faddf, v, 0x112);
    DPP_STEP_F(faddf, v, 0x114); DPP_STEP_F(faddf, v, 0x118);
    DPP_STEP_F(faddf, v, 0x142); DPP_STEP_F(faddf, v, 0x143);
    return __int_as_float(__builtin_amdgcn_readlane(__float_as_int(v), 63));
}

// ---------------------------------------------------------------------------
// Generic weight transpose + bf16 split, one 32x32 tile per call.
// Store phase packs adjacent-column pairs into u32 (half the instructions).
// ---------------------------------------------------------------------------
__device__ __forceinline__ void wsplit_tile(
    int bid, int tid, int nthr,
    const float* __restrict__ qkvw, const float* __restrict__ projw,
    const float* __restrict__ ff1w, const float* __restrict__ ff2w,
    ushort_t* __restrict__ th, ushort_t* __restrict__ tl,
    float (*T)[33]) {
    const float* src; int K, N; size_t dst;
    if (bid < 768)       { src = qkvw;  K = 512;  N = 1536; dst = 0;       }
    else if (bid < 1024) { src = projw; K = 512;  N = 512;  dst = 786432;  bid -= 768;  }
    else if (bid < 1536) { src = ff1w;  K = 512;  N = 1024; dst = 1048576; bid -= 1024; }
    else                 { src = ff2w;  K = 1024; N = 512;  dst = 1572864; bid -= 1536; }
    int ntn = N >> 5;
    int tn = bid % ntn, tk = bid / ntn;
    int n0 = tn * 32, k0 = tk * 32;
    for (int e = tid; e < 1024; e += nthr) {
        int r = e >> 5, c = e & 31;
        T[r][c] = src[(size_t)(k0 + r) * N + n0 + c];
    }
    __syncthreads();
    for (int e = tid; e < 512; e += nthr) {
        int r = e >> 4, cc = (e & 15) * 2;
        ushort_t h0, l0, h1, l1;
        split2(T[cc][r], h0, l0);
        split2(T[cc + 1][r], h1, l1);
        size_t o = dst + (size_t)(n0 + r) * K + k0 + cc;
        *(uint_t*)&th[o] = (uint_t)h0 | ((uint_t)h1 << 16);
        *(uint_t*)&tl[o] = (uint_t)l0 | ((uint_t)l1 << 16);
    }
}

// ---------------------------------------------------------------------------
__global__ __launch_bounds__(256) void build_pts_kernel(const float* __restrict__ points,
                                                        float* __restrict__ pts) {
    int i = blockIdx.x * 256 + threadIdx.x;   // over B*L*NPTS = 166400
    if (i >= BB * LL * NPTS) return;
    int n = i % NPTS;
    int bl = i / NPTS;
    if (n < NN) {
        const float* src = points + ((size_t)bl * NN + n) * 3;
        pts[(size_t)i * 3 + 0] = src[0];
        pts[(size_t)i * 3 + 1] = src[1];
        pts[(size_t)i * 3 + 2] = src[2];
    } else {
        int j = n - NN;
        int ix = j >> 4, iy = (j >> 2) & 3, iz = j & 3;
        pts[(size_t)i * 3 + 0] = -1.5f + (float)ix;
        pts[(size_t)i * 3 + 1] = -1.5f + (float)iy;
        pts[(size_t)i * 3 + 2] = -1.5f + (float)iz;
    }
}

// ---------------------------------------------------------------------------
// FPS (blocks 0..23, 256 thr = 4 waves) + wsplit for BOTH layer 0 (blocks
// 24..2071 -> buffer 0) and layer 1 (blocks 2072..4119 -> buffer 1): fps
// occupies only 24 CUs for ~170us, so both fills ride the idle capacity.
// ---------------------------------------------------------------------------
__global__ __launch_bounds__(256) void fps_ws_kernel(
    const float* __restrict__ pts, float* __restrict__ axyz,
    const float* __restrict__ qkvw, const float* __restrict__ projw,
    const float* __restrict__ ff1w, const float* __restrict__ ff2w,
    ushort_t* __restrict__ th, ushort_t* __restrict__ tl,
    const float* __restrict__ qkvw1, const float* __restrict__ projw1,
    const float* __restrict__ ff1w1, const float* __restrict__ ff2w1,
    ushort_t* __restrict__ th1, ushort_t* __restrict__ tl1) {
    __shared__ __align__(16) char smem[50048];
    int bid = blockIdx.x;
    int tid = threadIdx.x;
    if (bid >= 24) {
        int widx = bid - 24;
        if (widx < 2048)
            wsplit_tile(widx, tid, 256, qkvw, projw, ff1w, ff2w, th, tl,
                        (float(*)[33])smem);
        else
            wsplit_tile(widx - 2048, tid, 256, qkvw1, projw1, ff1w1, ff2w1,
                        th1, tl1, (float(*)[33])smem);
        return;
    }
    float* sx = (float*)smem;
    float* sy = sx + NPTS;
    float* sz = sy + NPTS;
    float* redv = sz + NPTS;          // [2][4]
    int* redi = (int*)(redv + 8);     // [2][4]

    int b = bid / 3, f = bid % 3;
    const float* P = pts + (size_t)(b * LL + 2 * f) * NPTS * 3;
    int lane = tid & 63, wid = tid >> 6;
    // thread t<64 owns 17 pts [17t..); t>=64 owns 16 starting 1088+16(t-64).
    int start = tid < 64 ? 17 * tid : 1088 + 16 * (tid - 64);
    float px[17], py[17], pz[17], dist[17];
#pragma unroll
    for (int j = 0; j < 16; j++) {
        int n = start + j;
        float gx = P[(size_t)n * 3 + 0];
        float gy = P[(size_t)n * 3 + 1];
        float gz = P[(size_t)n * 3 + 2];
        px[j] = gx; py[j] = gy; pz[j] = gz;
        sx[n] = gx; sy[n] = gy; sz[n] = gz;
        dist[j] = 1e10f;
    }
    if (tid < 64) {                   // wave-uniform (wave 0)
        int n = start + 16;
        float gx = P[(size_t)n * 3 + 0];
        float gy = P[(size_t)n * 3 + 1];
        float gz = P[(size_t)n * 3 + 2];
        px[16] = gx; py[16] = gy; pz[16] = gz;
        sx[n] = gx; sy[n] = gy; sz[n] = gz;
        dist[16] = 1e10f;
    } else {
        px[16] = 0.f; py[16] = 0.f; pz[16] = 0.f;
        dist[16] = -1.0f;
    }
    __syncthreads();
    float ax = sx[0], ay = sy[0], az = sz[0];
    float* out = axyz + (size_t)bid * MM * 3;
    for (int m = 0; m < MM; m++) {
        if (tid == 0) { out[m * 3 + 0] = ax; out[m * 3 + 1] = ay; out[m * 3 + 2] = az; }
        float bv = -1.0f;
        int bjn = start;
#pragma unroll
        for (int j = 0; j < 16; j++) {
            float d = sqdist_rn(px[j], py[j], pz[j], ax, ay, az);
            float dj = fminf(dist[j], d);
            dist[j] = dj;
            if (dj > bv) { bv = dj; bjn = start + j; }   // strict >: first j wins
        }
        if (tid < 64) {               // wave-uniform extra point
            float d = sqdist_rn(px[16], py[16], pz[16], ax, ay, az);
            float dj = fminf(dist[16], d);
            dist[16] = dj;
            if (dj > bv) { bv = dj; bjn = start + 16; }
        }
        float wmv = wave_max_bcast(bv);
        unsigned long long mk = __ballot(bv == wmv);
        int srcl = __ffsll(mk) - 1;   // lowest tied lane = smallest n
        int wn = __builtin_amdgcn_readlane(bjn, srcl);
        int par = (m & 1) * 4;        // ping-pong: iter m+1 writes other half
        if (lane == 0) { redv[par + wid] = wmv; redi[par + wid] = wn; }
        __syncthreads();
        float b0 = redv[par + 0], b1 = redv[par + 1];
        float b2 = redv[par + 2], b3 = redv[par + 3];
        int i0 = redi[par + 0], i1 = redi[par + 1];
        int i2 = redi[par + 2], i3 = redi[par + 3];
        float bb = b0; int bn = i0;                  // first-wins: wave order =
        if (b1 > bb) { bb = b1; bn = i1; }           // ascending n -> smallest n
        if (b2 > bb) { bb = b2; bn = i2; }
        if (b3 > bb) { bb = b3; bn = i3; }
        ax = sx[bn]; ay = sy[bn]; az = sz[bn];
    }
}

// ---------------------------------------------------------------------------
// Ball query + grouped conv + max over k + max over window + pos embedding.
// 4 anchors per 256-thr block (one wave each, per-wave LDS, no barriers).
// ---------------------------------------------------------------------------
__global__ __launch_bounds__(256) void group_conv_kernel(
    const float* __restrict__ pts, const float* __restrict__ axyz,
    const float* __restrict__ conv_d_w, const float* __restrict__ conv_f_w,
    const float* __restrict__ pos_w, const float* __restrict__ pos_b,
    float* __restrict__ x) {
    int wid = threadIdx.x >> 6;
    int gid = blockIdx.x * 4 + wid;       // b*780 + f*260 + m
    int b = gid / SSEQ;
    int rem = gid % SSEQ;
    int f = rem / MM;
    int lane = threadIdx.x & 63;
    const float* A = axyz + (size_t)gid * 3;
    float ax = A[0], ay = A[1], az = A[2];

    float cf0[8], cf1[8], cf2[8], cd0[8], cd1[8], cd2[8], cd3[8], fmx[8];
#pragma unroll
    for (int c = 0; c < 8; c++) {
        int d = lane + 64 * c;
        cf0[c] = conv_f_w[d * 3 + 0];
        cf1[c] = conv_f_w[d * 3 + 1];
        cf2[c] = conv_f_w[d * 3 + 2];
        cd0[c] = conv_d_w[d * 4 + 0];
        cd1[c] = conv_d_w[d * 4 + 1];
        cd2[c] = conv_d_w[d * 4 + 2];
        cd3[c] = conv_d_w[d * 4 + 3];
        fmx[c] = -INFINITY;
    }
    __shared__ int nbr[4][32];
    __shared__ float gxs[4][32], gys[4][32], gzs[4][32];
    const float R2 = 0.49000000953674316f;

    for (int wi = 0; wi < 3; wi++) {
        int l = 2 * f + wi - 1;
        l = l < 0 ? 0 : (l > 4 ? 4 : l);
        const float* P = pts + (size_t)(b * LL + l) * NPTS * 3;
        int cnt = 0;
        for (int base = 0; base < NPTS && cnt < 32; base += 64) {
            int n = base + lane;
            float d2 = sqdist_rn(P[(size_t)n * 3], P[(size_t)n * 3 + 1], P[(size_t)n * 3 + 2],
                                 ax, ay, az);
            bool hit = d2 < R2;
            unsigned long long mk = __ballot(hit);
            int rank = (int)__popcll(mk & (((unsigned long long)1 << lane) - 1ull));
            if (hit && (cnt + rank) < 32) nbr[wid][cnt + rank] = n;
            cnt += (int)__popcll(mk);
        }
        int eff = cnt < 32 ? cnt : 32;
        if (lane < 32) {
            int idx = (eff == 0) ? 0 : (lane < eff ? nbr[wid][lane] : nbr[wid][0]);
            gxs[wid][lane] = P[(size_t)idx * 3 + 0];
            gys[wid][lane] = P[(size_t)idx * 3 + 1];
            gzs[wid][lane] = P[(size_t)idx * 3 + 2];
        }
        float tf = (float)(wi - 1);
        for (int k = 0; k < 32; k++) {
            float gx = gxs[wid][k], gy = gys[wid][k], gz = gzs[wid][k];
            float dx = gx - ax, dy = gy - ay, dz = gz - az;
#pragma unroll
            for (int c = 0; c < 8; c++) {
                float v = gx * cf0[c] + gy * cf1[c] + gz * cf2[c] +
                          dx * cd0[c] + dy * cd1[c] + dz * cd2[c] + tf * cd3[c];
                fmx[c] = fmaxf(fmx[c], v);
            }
        }
    }
    float tcol = (float)(f + 1);
#pragma unroll
    for (int c = 0; c < 8; c++) {
        int d = lane + 64 * c;
        float pos = ax * pos_w[d * 4 + 0] + ay * pos_w[d * 4 + 1] +
                    az * pos_w[d * 4 + 2] + tcol * pos_w[d * 4 + 3] + pos_b[d];
        x[(size_t)gid * DIMC + d] = fmx[c] + pos;
    }
}

// ---------------------------------------------------------------------------
// LayerNorm over last dim 512; output written as bf16 hi/lo split (GEMM A).
// 4 rows per 256-thr block (one wave each, no cross-wave interaction).
// ---------------------------------------------------------------------------
__global__ __launch_bounds__(256) void ln_kernel(const float* __restrict__ x,
                                                 const float* __restrict__ g,
                                                 const float* __restrict__ b,
                                                 ushort_t* __restrict__ yh,
                                                 ushort_t* __restrict__ yl) {
    int r = blockIdx.x * 4 + (threadIdx.x >> 6);
    int lane = threadIdx.x & 63;
    const float* xr = x + (size_t)r * DIMC;
    float4 v0 = *(const float4*)(xr + lane * 8);
    float4 v1 = *(const float4*)(xr + lane * 8 + 4);
    float s = v0.x + v0.y + v0.z + v0.w + v1.x + v1.y + v1.z + v1.w;
    s = wave_sum_bcast(s);
    float mean = s * (1.0f / 512.0f);
    float dv[8];
    dv[0] = v0.x - mean; dv[1] = v0.y - mean; dv[2] = v0.z - mean; dv[3] = v0.w - mean;
    dv[4] = v1.x - mean; dv[5] = v1.y - mean; dv[6] = v1.z - mean; dv[7] = v1.w - mean;
    float sq = 0.f;
#pragma unroll
    for (int c = 0; c < 8; c++) sq += dv[c] * dv[c];
    sq = wave_sum_bcast(sq);
    float var = sq * (1.0f / 512.0f);
    float inv = 1.0f / sqrtf(var + 1e-5f);
    int d = lane * 8;
    ushort_t hs[8], ls[8];
#pragma unroll
    for (int c = 0; c < 8; c++) {
        float v = dv[c] * inv * g[d + c] + b[d + c];
        split2(v, hs[c], ls[c]);
    }
    uint4 hv, lv;
    hv.x = hs[0] | ((uint_t)hs[1] << 16); hv.y = hs[2] | ((uint_t)hs[3] << 16);
    hv.z = hs[4] | ((uint_t)hs[5] << 16); hv.w = hs[6] | ((uint_t)hs[7] << 16);
    lv.x = ls[0] | ((uint_t)ls[1] << 16); lv.y = ls[2] | ((uint_t)ls[3] << 16);
    lv.z = ls[4] | ((uint_t)ls[5] << 16); lv.w = ls[6] | ((uint_t)ls[7] << 16);
    *(uint4*)(yh + (size_t)r * DIMC + d) = hv;
    *(uint4*)(yl + (size_t)r * DIMC + d) = lv;
}

// ---------------------------------------------------------------------------
// bf16x3 MFMA GEMM (fp32 emulation): C = A @ W.
// Structure: stage -> barrier -> ds_read frags -> MFMA -> barrier; staging
// latency hidden by TLP.  Bijective XCD-aware block swizzle for L2 locality.
// EPI: 0 = fp32 C; 2 = bias+gelu -> split (Ch,Cl); 3 = bias+R -> C;
//      5 = qkv: Q/K cols -> split (Ch,Cl) stride 1024; V cols -> transposed
//          vT[(b*8+h)*64+d][key] split (Vh,Vl), key pitch VPITCH; V-writes
//          packed u64 (4 consecutive keys, never straddles a batch).
// ---------------------------------------------------------------------------
#define BK 32   // k per step (LDS row length in ushorts)

template <int BN, int EPI>
__global__ __launch_bounds__(256) void gemm_mfma(
    const ushort_t* __restrict__ Ahg, const ushort_t* __restrict__ Alg,
    const ushort_t* __restrict__ Bhg, const ushort_t* __restrict__ Blg,
    const float* __restrict__ bias, const float* __restrict__ R,
    float* __restrict__ C, ushort_t* __restrict__ Ch, ushort_t* __restrict__ Cl,
    ushort_t* __restrict__ Vh, ushort_t* __restrict__ Vl,
    int M, int N, int K) {
    const int WN = BN / 2, NT = WN / 16;
    __shared__ __align__(16) ushort_t Ah[128 * BK];
    __shared__ __align__(16) ushort_t Al[128 * BK];
    __shared__ __align__(16) ushort_t Bh[BN * BK];
    __shared__ __align__(16) ushort_t Bl[BN * BK];
    int tid = threadIdx.x;
    int lane = tid & 63, w = tid >> 6;
    int wm = w & 1, wn = w >> 1;
    int quad = lane >> 4, l15 = lane & 15;

    // bijective XCD swizzle (T1): each XCD gets a contiguous chunk of linear
    // block ids -> consecutive row-blocks share A panels in the XCD's L2.
    int nx = gridDim.x;
    int nwg = nx * gridDim.y;
    int lid = blockIdx.x + nx * blockIdx.y;
    int q = nwg >> 3, r = nwg & 7;
    int xcd = lid & 7, off = lid >> 3;
    int nid = (xcd < r ? xcd * (q + 1) : r * (q + 1) + (xcd - r) * q) + off;
    int m0 = (nid / nx) * 128, n0 = (nid % nx) * BN;

    // staging geometry: one gload16 stages a 16-row group; lane l -> row l>>2,
    // 16B chunk l&3 (linear dest). Source chunk pre-swizzled by (row>>1)&3.
    int sr = lane >> 2;
    int sc = lane & 3;
    int kq = ((sc ^ ((sr >> 1) & 3)) << 3);   // swizzled ushort k-offset [0,32)

    int aoff[2];
#pragma unroll
    for (int i = 0; i < 2; i++) {
        int g = w + 4 * i;
        int row = m0 + g * 16 + sr; if (row >= M) row = M - 1;
        aoff[i] = row * K + kq;
    }
    int boff[BN == 128 ? 2 : 1];
    if (BN == 128) {
#pragma unroll
        for (int i = 0; i < 2; i++) {
            int g = w + 4 * i;
            boff[i] = (n0 + g * 16 + sr) * K + kq;
        }
    } else {
        boff[0] = (n0 + w * 16 + sr) * K + kq;
    }

    fx4 acc[4][NT];
#pragma unroll
    for (int mi = 0; mi < 4; mi++)
#pragma unroll
        for (int nj = 0; nj < NT; nj++) acc[mi][nj] = (fx4){0.f, 0.f, 0.f, 0.f};

    // fragment-read addresses (swizzled 16B chunk; same XOR as the source)
    int rsw = (l15 >> 1) & 3;
    int aro = (64 * wm + l15) * BK + ((quad ^ rsw) << 3);
    int bro = (WN * wn + l15) * BK + ((quad ^ rsw) << 3);

    for (int k0 = 0; k0 < K; k0 += BK) {
#pragma unroll
        for (int i = 0; i < 2; i++) {
            int g = w + 4 * i;
            gload16(Ahg + aoff[i] + k0, &Ah[g * 16 * BK]);
            gload16(Alg + aoff[i] + k0, &Al[g * 16 * BK]);
        }
        if (BN == 128) {
#pragma unroll
            for (int i = 0; i < 2; i++) {
                int g = w + 4 * i;
                gload16(Bhg + boff[i] + k0, &Bh[g * 16 * BK]);
                gload16(Blg + boff[i] + k0, &Bl[g * 16 * BK]);
            }
        } else {
            gload16(Bhg + boff[0] + k0, &Bh[w * 16 * BK]);
            gload16(Blg + boff[0] + k0, &Bl[w * 16 * BK]);
        }
        __syncthreads();   // drains vmcnt(0): staged data visible

        s16x8 bf[NT][2];
#pragma unroll
        for (int nj = 0; nj < NT; nj++) {
            bf[nj][0] = *(const s16x8*)&Bh[bro + 16 * nj * BK];
            bf[nj][1] = *(const s16x8*)&Bl[bro + 16 * nj * BK];
        }
#pragma unroll
        for (int mi = 0; mi < 4; mi++) {
            s16x8 aH = *(const s16x8*)&Ah[aro + 16 * mi * BK];
            s16x8 aL = *(const s16x8*)&Al[aro + 16 * mi * BK];
#pragma unroll
            for (int nj = 0; nj < NT; nj++) {
                acc[mi][nj] = __builtin_amdgcn_mfma_f32_16x16x32_bf16(aH, bf[nj][0], acc[mi][nj], 0, 0, 0);
                acc[mi][nj] = __builtin_amdgcn_mfma_f32_16x16x32_bf16(aH, bf[nj][1], acc[mi][nj], 0, 0, 0);
                acc[mi][nj] = __builtin_amdgcn_mfma_f32_16x16x32_bf16(aL, bf[nj][0], acc[mi][nj], 0, 0, 0);
            }
        }
        __syncthreads();   // all reads done before next step's DMA overwrites
    }
    if (EPI == 5) {
#pragma unroll
        for (int mi = 0; mi < 4; mi++) {
#pragma unroll
            for (int nj = 0; nj < NT; nj++) {
                int col = n0 + WN * wn + 16 * nj + l15;
                int row0 = m0 + 64 * wm + 16 * mi + quad * 4;
                if (row0 < M) {       // rows row0..row0+3 all valid (M%4==0)
                    if (col < 1024) {
#pragma unroll
                        for (int r2 = 0; r2 < 4; r2++) {
                            ushort_t h, l;
                            split2(acc[mi][nj][r2], h, l);
                            Ch[(size_t)(row0 + r2) * 1024 + col] = h;
                            Cl[(size_t)(row0 + r2) * 1024 + col] = l;
                        }
                    } else {
                        int bb = row0 / SSEQ, key0 = row0 % SSEQ;
                        int hh = (col - 1024) >> 6, dd = (col - 1024) & 63;
                        size_t vo = ((size_t)((bb * 8 + hh) * 64 + dd)) * VPITCH + key0;
                        u64_t ph = 0, pl = 0;
#pragma unroll
                        for (int r2 = 0; r2 < 4; r2++) {
                            ushort_t h, l;
                            split2(acc[mi][nj][r2], h, l);
                            ph |= (u64_t)h << (16 * r2);
                            pl |= (u64_t)l << (16 * r2);
                        }
                        *(u64_t*)(Vh + vo) = ph;
                        *(u64_t*)(Vl + vo) = pl;
                    }
                }
            }
        }
    } else {
#pragma unroll
        for (int mi = 0; mi < 4; mi++) {
#pragma unroll
            for (int r2 = 0; r2 < 4; r2++) {
                int row = m0 + 64 * wm + 16 * mi + quad * 4 + r2;
                if (row < M) {
#pragma unroll
                    for (int nj = 0; nj < NT; nj++) {
                        int col = n0 + WN * wn + 16 * nj + l15;
                        float v = acc[mi][nj][r2];
                        if (EPI == 0) {
                            C[(size_t)row * N + col] = v;
                        } else if (EPI == 3) {
                            C[(size_t)row * N + col] = v + bias[col] + R[(size_t)row * N + col];
                        } else if (EPI == 2) {
                            float gv = gelu_exact(v + bias[col]);
                            ushort_t h, l;
                            split2(gv, h, l);
                            Ch[(size_t)row * N + col] = h;
                            Cl[(size_t)row * N + col] = l;
                        }
                    }
                }
            }
        }
    }
}

// ---------------------------------------------------------------------------
// MFMA flash attention (lid < 448) + next-layer wsplit (lid >= 448, only for
// layers 1..3 -> fills buffer (l+1)&1; layers 0 and 4 launch attn-only).
// QBLK=128, 8 waves; Q in registers; K/V via global_load_lds + both-sides
// XOR swizzle; XCD grouping (7 qt-blocks of a (b,h) share lid%8); swapped
// QK^T with packed ds_write_b64 P-store; s_setprio around MFMA clusters.
// ---------------------------------------------------------------------------
#define KP2 64     // K/V LDS pitch (ushorts): linear rows for gload16
#define PP 72      // P LDS pitch (ushorts)
#define NATTN 448  // 7 qt * 64 bh

__global__ __launch_bounds__(512, 4) void attn_mfma_kernel(
    const ushort_t* __restrict__ qkh, const ushort_t* __restrict__ qkl,
    const ushort_t* __restrict__ vth, const ushort_t* __restrict__ vtl,
    ushort_t* __restrict__ oh, ushort_t* __restrict__ ol,
    const float* __restrict__ nqkvw, const float* __restrict__ nprojw,
    const float* __restrict__ nff1w, const float* __restrict__ nff2w,
    ushort_t* __restrict__ nth, ushort_t* __restrict__ ntl) {
    __shared__ __align__(16) char smem[69632];
    int lid = blockIdx.x;
    if (lid >= NATTN) {
        int widx = lid - NATTN;
        wsplit_tile(widx, threadIdx.x, 512, nqkvw, nprojw, nff1w, nff2w,
                    nth, ntl, (float(*)[33])smem);
        return;
    }
    // XCD-grouped decode: xcd residue = lid&7; idx = lid>>3 in [0,56):
    // qt = idx%7, bh = (lid&7)*8 + idx/7  -> all qt of a bh share lid%8.
    int xcd = lid & 7, idx = lid >> 3;
    int qt = idx % 7;
    int bh = xcd * 8 + idx / 7;
    int b = bh >> 3, h = bh & 7;

    ushort_t* Kh  = (ushort_t*)smem;          // 64 x KP2 each
    ushort_t* Kl  = Kh + 64 * KP2;
    ushort_t* Vth = Kl + 64 * KP2;
    ushort_t* Vtl = Vth + 64 * KP2;
    ushort_t* Ph  = Vtl + 64 * KP2;           // 128 x PP each
    ushort_t* Pl  = Ph + 128 * PP;

    int tid = threadIdx.x;
    int lane = tid & 63, w = tid >> 6;        // w in 0..7
    int quad = lane >> 4, l15 = lane & 15;

    int q0 = qt * 128;
    int nq = SSEQ - q0; if (nq > 128) nq = 128;

    // Q fragments in registers: wave w's rows 16w..16w+15, both 32-k chunks.
    s16x8 qfh[2], qfl[2];
    {
        int row = 16 * w + l15;
        int gq = q0 + (row < nq ? row : nq - 1);
        size_t go = (size_t)(b * SSEQ + gq) * 1024 + h * 64;
#pragma unroll
        for (int ks = 0; ks < 2; ks++) {
            qfh[ks] = *(const s16x8*)(qkh + go + 32 * ks + quad * 8);
            qfl[ks] = *(const s16x8*)(qkl + go + 32 * ks + quad * 8);
        }
    }

    fx4 accO[4];
#pragma unroll
    for (int dj = 0; dj < 4; dj++) accO[dj] = (fx4){0.f, 0.f, 0.f, 0.f};
    fx4 accL = (fx4){0.f, 0.f, 0.f, 0.f};

    s16x8 ones;
#pragma unroll
    for (int j = 0; j < 8; j++) ones[j] = (short)16256;   // bf16 1.0

    // staging geometry: one gload16 group = 8 rows x 8 chunks = 1KB, wave-
    // uniform dest base; lane -> row lane>>3, chunk lane&7, source chunk
    // pre-swizzled by row&7 (read side applies the same XOR).
    int sr8 = lane >> 3;
    int csw = (lane & 7) ^ sr8;

    // fragment chunk offsets: global chunk g = 4*ks+quad at LDS row r lives
    // at chunk g^(r&7); r&7 == l15&7 for all fragment rows used below.
    int r7 = l15 & 7;
    int c0 = (quad ^ r7) * 8;          // ks = 0 (ushort offset)
    int c1 = ((quad ^ r7) ^ 4) * 8;    // ks = 1

    for (int kt = 0; kt < 13; kt++) {
        int k0 = kt * 64;
        int nk = SSEQ - k0; if (nk > 64) nk = 64;
        __syncthreads();   // prior QK/PV reads done before DMA overwrite
        {
            int row = w * 8 + sr8;     // 8 waves x 8 rows = 64 rows
            int gk = k0 + (row < nk ? row : nk - 1);
            size_t go = (size_t)(b * SSEQ + gk) * 1024 + h * 64 + 512 + csw * 8;
            gload16(qkh + go, Kh + w * 512);
            gload16(qkl + go, Kl + w * 512);
            size_t vo = ((size_t)(bh * 64 + row)) * VPITCH + k0 + csw * 8;
            gload16(vth + vo, Vth + w * 512);
            gload16(vtl + vo, Vtl + w * 512);
        }
        __syncthreads();   // vmcnt drained: tiles visible

        // S^T tile via swapped operands: A = K rows (keys), B = Q regs.
        // accS[nj][r] = S[q = 16w+l15][key = 16nj + quad*4 + r].
        fx4 accS[4];
#pragma unroll
        for (int nj = 0; nj < 4; nj++) accS[nj] = (fx4){0.f, 0.f, 0.f, 0.f};
        __builtin_amdgcn_s_setprio(1);
#pragma unroll
        for (int ks = 0; ks < 2; ks++) {
            int ca = ks ? c1 : c0;
            s16x8 bQh = qfh[ks];
            s16x8 bQl = qfl[ks];
#pragma unroll
            for (int nj = 0; nj < 4; nj++) {
                s16x8 aKh = *(const s16x8*)&Kh[(16 * nj + l15) * KP2 + ca];
                s16x8 aKl = *(const s16x8*)&Kl[(16 * nj + l15) * KP2 + ca];
                accS[nj] = __builtin_amdgcn_mfma_f32_16x16x32_bf16(aKh, bQh, accS[nj], 0, 0, 0);
                accS[nj] = __builtin_amdgcn_mfma_f32_16x16x32_bf16(aKl, bQh, accS[nj], 0, 0, 0);
                accS[nj] = __builtin_amdgcn_mfma_f32_16x16x32_bf16(aKh, bQl, accS[nj], 0, 0, 0);
            }
        }
        __builtin_amdgcn_s_setprio(0);
        // P = exp(S * scale): lane owns q-row 16w+l15, 4 consecutive keys per
        // nj -> pack hi/lo into u64 and store with ds_write_b64.
        {
            int qrow = 16 * w + l15;
#pragma unroll
            for (int nj = 0; nj < 4; nj++) {
                int kbase = 16 * nj + quad * 4;
                u64_t ph = 0, pl = 0;
#pragma unroll
                for (int r = 0; r < 4; r++) {
                    float s = accS[nj][r] * 0.125f;
                    float p = (kbase + r < nk) ? __expf(s) : 0.f;
                    ushort_t hh, ll;
                    split2(p, hh, ll);
                    ph |= (u64_t)hh << (16 * r);
                    pl |= (u64_t)ll << (16 * r);
                }
                *(u64_t*)&Ph[qrow * PP + kbase] = ph;
                *(u64_t*)&Pl[qrow * PP + kbase] = pl;
            }
        }
        // PV (x3) + l-sum (ones-B); wave-local, in-order DS => no barrier
        __builtin_amdgcn_s_setprio(1);
#pragma unroll
        for (int ks = 0; ks < 2; ks++) {
            int ca = ks ? c1 : c0;
            s16x8 aPh = *(const s16x8*)&Ph[(16 * w + l15) * PP + 32 * ks + quad * 8];
            s16x8 aPl = *(const s16x8*)&Pl[(16 * w + l15) * PP + 32 * ks + quad * 8];
            accL = __builtin_amdgcn_mfma_f32_16x16x32_bf16(aPh, ones, accL, 0, 0, 0);
            accL = __builtin_amdgcn_mfma_f32_16x16x32_bf16(aPl, ones, accL, 0, 0, 0);
#pragma unroll
            for (int dj = 0; dj < 4; dj++) {
                s16x8 bVh = *(const s16x8*)&Vth[(16 * dj + l15) * KP2 + ca];
                s16x8 bVl = *(const s16x8*)&Vtl[(16 * dj + l15) * KP2 + ca];
                accO[dj] = __builtin_amdgcn_mfma_f32_16x16x32_bf16(aPh, bVh, accO[dj], 0, 0, 0);
                accO[dj] = __builtin_amdgcn_mfma_f32_16x16x32_bf16(aPh, bVl, accO[dj], 0, 0, 0);
                accO[dj] = __builtin_amdgcn_mfma_f32_16x16x32_bf16(aPl, bVh, accO[dj], 0, 0, 0);
            }
        }
        __builtin_amdgcn_s_setprio(0);
    }
    // store O / l ; rows of accL align with rows of accO (C-layout)
#pragma unroll
    for (int r = 0; r < 4; r++) {
        int lq = 16 * w + quad * 4 + r;
        if (lq < nq) {
            float inv = 1.0f / accL[r];
            size_t base = (size_t)(b * SSEQ + q0 + lq) * DIMC + h * 64 + l15;
#pragma unroll
            for (int dj = 0; dj < 4; dj++) {
                ushort_t hh, ll;
                split2(accO[dj][r] * inv, hh, ll);
                oh[base + 16 * dj] = hh;
                ol[base + 16 * dj] = ll;
            }
        }
    }
}

// ---------------------------------------------------------------------------
// Head: fused max-pool (rows 0..779 in order == chunk-major order of the old
// two-stage version; fmax is exact-associative) + LayerNorm.
// ---------------------------------------------------------------------------
__global__ __launch_bounds__(512) void pool_ln_kernel(const float* __restrict__ x,
                                                      const float* __restrict__ g,
                                                      const float* __restrict__ b,
                                                      float* __restrict__ out) {
    int bb = blockIdx.x;
    int d = threadIdx.x;
    const float* xb = x + (size_t)(bb * SSEQ) * DIMC + d;
    float m = -INFINITY;
#pragma unroll 4
    for (int s = 0; s < SSEQ; s++) m = fmaxf(m, xb[(size_t)s * DIMC]);
    __shared__ float col[512];
    __shared__ float red[512];
    col[d] = m;
    red[d] = m;
    __syncthreads();
    for (int s = 256; s > 0; s >>= 1) {
        if (d < s) red[d] += red[d + s];
        __syncthreads();
    }
    float mean = red[0] * (1.0f / 512.0f);
    __syncthreads();
    float dv = col[d] - mean;
    red[d] = dv * dv;
    __syncthreads();
    for (int s = 256; s > 0; s >>= 1) {
        if (d < s) red[d] += red[d + s];
        __syncthreads();
    }
    float var = red[0] * (1.0f / 512.0f);
    float inv = 1.0f / sqrtf(var + 1e-5f);
    out[(size_t)bb * DIMC + d] = dv * inv * g[d] + b[d];
}

__global__ __launch_bounds__(256) void head1_kernel(const float* __restrict__ in,
                                                    const float* __restrict__ W,
                                                    const float* __restrict__ bias,
                                                    float* __restrict__ out) {
    int g = blockIdx.x, bb = blockIdx.y;
    int tid = threadIdx.x;
    int c = tid & 63, ks = tid >> 6;
    int col = g * 64 + c;
    __shared__ float xr[512];
    xr[tid] = in[(size_t)bb * 512 + tid];
    xr[tid + 256] = in[(size_t)bb * 512 + tid + 256];
    __syncthreads();
    float acc = 0.f;
    const float* Wc = W + col;
    for (int k = ks * 128; k < ks * 128 + 128; k++)
        acc += xr[k] * Wc[(size_t)k * MLPD];
    __shared__ float red[256];
    red[tid] = acc;
    __syncthreads();
    if (ks == 0) {
        float v = red[c] + red[c + 64] + red[c + 128] + red[c + 192] + bias[col];
        out[(size_t)bb * MLPD + col] = gelu_exact(v);
    }
}

// head2 + softmax-anchor fused: grid (17, BB) == smax's 136 groups; the
// ks==0 reduction lanes are exactly wave 0's 64 lanes -> run the wave-level
// softmax + anchor expectation in-place (identical value sequence to the
// former smax_anchor_kernel) and write the final output directly.
__global__ __launch_bounds__(256) void head2_kernel(const float* __restrict__ in,
                                                    const float* __restrict__ W,
                                                    const float* __restrict__ bias,
                                                    float* __restrict__ out) {
    int g = blockIdx.x, bb = blockIdx.y;
    int tid = threadIdx.x;
    int c = tid & 63, ks = tid >> 6;
    int col = g * 64 + c;
    __shared__ float xr[1024];
    xr[tid] = in[(size_t)bb * 1024 + tid];
    xr[tid + 256] = in[(size_t)bb * 1024 + tid + 256];
    xr[tid + 512] = in[(size_t)bb * 1024 + tid + 512];
    xr[tid + 768] = in[(size_t)bb * 1024 + tid + 768];
    __syncthreads();
    float acc = 0.f;
    const float* Wc = W + col;
    for (int k = ks * 256; k < ks * 256 + 256; k++)
        acc += xr[k] * Wc[(size_t)k * OUTD];
    __shared__ float red[256];
    red[tid] = acc;
    __syncthreads();
    if (ks == 0) {   // all 64 lanes of wave 0: full wave active for DPP ops
        float v = red[c] + red[c + 64] + red[c + 128] + red[c + 192] + bias[col];
        float mx = wave_max_bcast(v);
        float p = expf(v - mx);
        float sum = wave_sum_bcast(p);
        int ix = c >> 4, iy = (c >> 2) & 3, iz = c & 3;
        float sx = wave_sum_bcast(p * (-1.5f + (float)ix));
        float sy = wave_sum_bcast(p * (-1.5f + (float)iy));
        float sz = wave_sum_bcast(p * (-1.5f + (float)iz));
        if (c == 0) {
            float* o = out + ((size_t)bb * 17 + g) * 3;
            o[0] = sx / sum;
            o[1] = sy / sum;
            o[2] = sz / sum;
        }
    }
}

// ---------------------------------------------------------------------------
extern "C" void kernel_launch(void* const* d_in, const int* in_sizes, int n_in,
                              void* d_out, int out_size, void* d_ws, size_t ws_size,
                              hipStream_t stream) {
    const float* points     = (const float*)d_in[0];
    const float* conv_d_w   = (const float*)d_in[1];
    const float* conv_f_w   = (const float*)d_in[2];
    const float* pos_w      = (const float*)d_in[3];
    const float* pos_b      = (const float*)d_in[4];
    const float* ln1_g      = (const float*)d_in[5];
    const float* ln1_b      = (const float*)d_in[6];
    const float* qkv_w      = (const float*)d_in[7];
    const float* attn_out_w = (const float*)d_in[8];
    const float* attn_out_b = (const float*)d_in[9];
    const float* ln2_g      = (const float*)d_in[10];
    const float* ln2_b      = (const float*)d_in[11];
    const float* ff1_w      = (const float*)d_in[12];
    const float* ff1_b      = (const float*)d_in[13];
    const float* ff2_w      = (const float*)d_in[14];
    const float* ff2_b      = (const float*)d_in[15];
    const float* head_ln_g  = (const float*)d_in[16];
    const float* head_ln_b  = (const float*)d_in[17];
    const float* head1_w    = (const float*)d_in[18];
    const float* head1_b    = (const float*)d_in[19];
    const float* head2_w    = (const float*)d_in[20];
    const float* head2_b    = (const float*)d_in[21];

    // fp32 region
    float* ws = (float*)d_ws;
    float* pts    = ws;                    //   499,200 f
    float* axyz   = pts + 499200;          //    18,720 f
    float* xbuf   = axyz + 18720;          // 3,194,880 f
    float* qkvreg = xbuf + 3194880;        // 9,601,024 f (qk + vT, hi/lo)
    float* pooled = qkvreg + 9601024;      //     4,096 f
    float* h1     = pooled + 4096;         //     8,192 f
    float* h2     = h1 + 8192;             //     8,704 f (unused after fusion)
    float* fend   = h2 + 8704;
    // qk (stride 1024) + vT hi/lo inside qkvreg
    ushort_t* qkh = (ushort_t*)qkvreg;             // 6,389,760 us
    ushort_t* qkl = qkh + 6389760;                 // 6,389,760 us
    ushort_t* vth = qkl + 6389760;                 // 3,211,264 us (8*8*64*784)
    ushort_t* vtl = vth + 3211264;                 // 3,211,264 us
    // bf16 hi/lo region (ushort)
    ushort_t* us   = (ushort_t*)fend;
    ushort_t* xnh  = us;                   // 3,194,880 us
    ushort_t* xnl  = xnh + 3194880;
    ushort_t* atth = xnl + 3194880;
    ushort_t* attl = atth + 3194880;
    ushort_t* ffhh = attl + 3194880;       // 6,389,760 us
    ushort_t* ffhl = ffhh + 6389760;
    ushort_t* wbh  = ffhl + 6389760;       // 2 x WBUFSZ (ping-pong weights, hi)
    ushort_t* wbl  = wbh + 2 * WBUFSZ;     // 2 x WBUFSZ (lo)

    build_pts_kernel<<<650, 256, 0, stream>>>(points, pts);
    // fps + wsplit for layer 0 (buf0) AND layer 1 (buf1): both ride the
    // ~230 idle CUs during fps's 170us serial phase.
    fps_ws_kernel<<<24 + 4096, 256, 0, stream>>>(
        pts, axyz, qkv_w, attn_out_w, ff1_w, ff2_w, wbh, wbl,
        qkv_w + (size_t)1 * 512 * 1536, attn_out_w + (size_t)1 * 512 * 512,
        ff1_w + (size_t)1 * 512 * 1024, ff2_w + (size_t)1 * 1024 * 512,
        wbh + WBUFSZ, wbl + WBUFSZ);
    group_conv_kernel<<<NROWS / 4, 256, 0, stream>>>(pts, axyz, conv_d_w, conv_f_w,
                                                     pos_w, pos_b, xbuf);
    const int MB = (NROWS + 127) / 128;    // 49 row-blocks
    for (int l = 0; l < 5; l++) {
        ushort_t* wth = wbh + (size_t)(l & 1) * WBUFSZ;
        ushort_t* wtl = wbl + (size_t)(l & 1) * WBUFSZ;
        ushort_t* nth = wbh + (size_t)((l + 1) & 1) * WBUFSZ;
        ushort_t* ntl = wbl + (size_t)((l + 1) & 1) * WBUFSZ;
        int ln2off = l * 512;
        ln_kernel<<<NROWS / 4, 256, 0, stream>>>(xbuf, ln1_g + ln2off, ln1_b + ln2off, xnh, xnl);
        gemm_mfma<128, 5><<<dim3(1536 / 128, MB), 256, 0, stream>>>(
            xnh, xnl, wth, wtl, nullptr, nullptr, nullptr, qkh, qkl, vth, vtl,
            NROWS, 1536, 512);
        // attn; layers 1..3 also wsplit layer l+1 into buffer (l+1)&1.
        bool dofill = (l >= 1 && l < 4);
        int lnx = l + 1;
        attn_mfma_kernel<<<dim3(dofill ? NATTN + 2048 : NATTN), 512, 0, stream>>>(
            qkh, qkl, vth, vtl, atth, attl,
            dofill ? qkv_w + (size_t)lnx * 512 * 1536 : nullptr,
            dofill ? attn_out_w + (size_t)lnx * 512 * 512 : nullptr,
            dofill ? ff1_w + (size_t)lnx * 512 * 1024 : nullptr,
            dofill ? ff2_w + (size_t)lnx * 1024 * 512 : nullptr,
            nth, ntl);
        gemm_mfma<64, 3><<<dim3(512 / 64, MB), 256, 0, stream>>>(
            atth, attl, wth + 786432, wtl + 786432, attn_out_b + ln2off, xbuf,
            xbuf, nullptr, nullptr, nullptr, nullptr, NROWS, 512, 512);
        ln_kernel<<<NROWS / 4, 256, 0, stream>>>(xbuf, ln2_g + ln2off, ln2_b + ln2off, xnh, xnl);
        gemm_mfma<128, 2><<<dim3(1024 / 128, MB), 256, 0, stream>>>(
            xnh, xnl, wth + 1048576, wtl + 1048576, ff1_b + l * 1024, nullptr,
            nullptr, ffhh, ffhl, nullptr, nullptr, NROWS, 1024, 512);
        gemm_mfma<64, 3><<<dim3(512 / 64, MB), 256, 0, stream>>>(
            ffhh, ffhl, wth + 1572864, wtl + 1572864, ff2_b + ln2off, xbuf,
            xbuf, nullptr, nullptr, nullptr, nullptr, NROWS, 512, 1024);
    }
    pool_ln_kernel<<<BB, 512, 0, stream>>>(xbuf, head_ln_g, head_ln_b, pooled);
    head1_kernel<<<dim3(16, BB), 256, 0, stream>>>(pooled, head1_w, head1_b, h1);
    head2_kernel<<<dim3(17, BB), 256, 0, stream>>>(h1, head2_w, head2_b, (float*)d_out);
}

// Round 11
// 1650.889 us; speedup vs baseline: 1.0309x; 1.0309x over previous
//
#include <hip/hip_runtime.h>
#include <hip/hip_bf16.h>
#include <cstddef>

// Problem constants
#define BB 8
#define LL 5
#define NN 4096
#define NANCH 64
#define NPTS 4160      // NN + NANCH
#define MM 260         // NPTS / 16
#define NFRAME 3
#define SSEQ 780       // NFRAME * MM
#define DIMC 512
#define NHEAD 8
#define DHEAD 64
#define MLPD 1024
#define OUTD 1088
#define NROWS 6240     // BB * SSEQ
#define VPITCH 784     // vT key pitch (780 padded to 16B-aligned rows)
#define WBUFSZ 2097152 // ushorts per weight buffer (qkv|proj|ff1|ff2)

typedef __attribute__((ext_vector_type(8))) short s16x8;
typedef __attribute__((ext_vector_type(4))) float fx4;
typedef unsigned short ushort_t;
typedef unsigned int uint_t;
typedef unsigned long long u64_t;

// exact (non-contracted) squared distance, matching numpy fp32 op order
__device__ __forceinline__ float sqdist_rn(float x1, float y1, float z1,
                                           float x2, float y2, float z2) {
    float dx = __fsub_rn(x1, x2);
    float dy = __fsub_rn(y1, y2);
    float dz = __fsub_rn(z1, z2);
    return __fadd_rn(__fadd_rn(__fmul_rn(dx, dx), __fmul_rn(dy, dy)), __fmul_rn(dz, dz));
}

__device__ __forceinline__ float gelu_exact(float v) {
    return 0.5f * v * (1.0f + erff(v * 0.70710678118654752440f));
}

// round-to-nearest bf16
__device__ __forceinline__ uint_t bf16rn(float f) {
    uint_t u = __float_as_uint(f);
    return (u + 0x7FFFu + ((u >> 16) & 1u)) >> 16;
}
// split fp32 into bf16 hi + bf16 lo (residual)
__device__ __forceinline__ void split2(float f, ushort_t& h, ushort_t& l) {
    uint_t hb = bf16rn(f);
    h = (ushort_t)hb;
    float fh = __uint_as_float(hb << 16);
    l = (ushort_t)bf16rn(f - fh);
}

// async global->LDS (16B per lane; dest = wave-uniform base + lane*16)
typedef __attribute__((address_space(3))) unsigned int as3u;
typedef const __attribute__((address_space(1))) unsigned int as1u;
__device__ __forceinline__ void gload16(const ushort_t* g, ushort_t* l) {
    __builtin_amdgcn_global_load_lds((as1u*)g, (as3u*)l, 16, 0, 0);
}

// ---- DPP wave64 reductions. ctrl must be an immediate -> template param.
template <int CTRL>
__device__ __forceinline__ int dpp_mov(int v) {
    return __builtin_amdgcn_update_dpp(0, v, CTRL, 0xF, 0xF, true);
}
#define DPP_STEP_F(op, v, ctrl) v = op(v, __int_as_float(dpp_mov<ctrl>(__float_as_int(v))))
__device__ __forceinline__ float wave_max_bcast(float v) {
    DPP_STEP_F(fmaxf, v, 0x111); DPP_STEP_F(fmaxf, v, 0x112);
    DPP_STEP_F(fmaxf, v, 0x114); DPP_STEP_F(fmaxf, v, 0x118);
    DPP_STEP_F(fmaxf, v, 0x142); DPP_STEP_F(fmaxf, v, 0x143);
    return __int_as_float(__builtin_amdgcn_readlane(__float_as_int(v), 63));
}
__device__ __forceinline__ float faddf(float a, float b) { return a + b; }
__device__ __forceinline__ float wave_sum_bcast(float v) {
    DPP_STEP_F(faddf, v, 0x111); DPP_STEP_F(faddf, v, 0x112);
    DPP_STEP_F(faddf, v, 0x114); DPP_STEP_F(faddf, v, 0x118);
    DPP_STEP_F(faddf, v, 0x142); DPP_STEP_F(faddf, v, 0x143);
    return __int_as_float(__builtin_amdgcn_readlane(__float_as_int(v), 63));
}

// ---------------------------------------------------------------------------
// Generic weight transpose + bf16 split, one 32x32 tile per call.
// Store phase packs adjacent-column pairs into u32 (half the instructions).
// ---------------------------------------------------------------------------
__device__ __forceinline__ void wsplit_tile(
    int bid, int tid, int nthr,
    const float* __restrict__ qkvw, const float* __restrict__ projw,
    const float* __restrict__ ff1w, const float* __restrict__ ff2w,
    ushort_t* __restrict__ th, ushort_t* __restrict__ tl,
    float (*T)[33]) {
    const float* src; int K, N; size_t dst;
    if (bid < 768)       { src = qkvw;  K = 512;  N = 1536; dst = 0;       }
    else if (bid < 1024) { src = projw; K = 512;  N = 512;  dst = 786432;  bid -= 768;  }
    else if (bid < 1536) { src = ff1w;  K = 512;  N = 1024; dst = 1048576; bid -= 1024; }
    else                 { src = ff2w;  K = 1024; N = 512;  dst = 1572864; bid -= 1536; }
    int ntn = N >> 5;
    int tn = bid % ntn, tk = bid / ntn;
    int n0 = tn * 32, k0 = tk * 32;
    for (int e = tid; e < 1024; e += nthr) {
        int r = e >> 5, c = e & 31;
        T[r][c] = src[(size_t)(k0 + r) * N + n0 + c];
    }
    __syncthreads();
    for (int e = tid; e < 512; e += nthr) {
        int r = e >> 4, cc = (e & 15) * 2;
        ushort_t h0, l0, h1, l1;
        split2(T[cc][r], h0, l0);
        split2(T[cc + 1][r], h1, l1);
        size_t o = dst + (size_t)(n0 + r) * K + k0 + cc;
        *(uint_t*)&th[o] = (uint_t)h0 | ((uint_t)h1 << 16);
        *(uint_t*)&tl[o] = (uint_t)l0 | ((uint_t)l1 << 16);
    }
}

// ---------------------------------------------------------------------------
__global__ __launch_bounds__(256) void build_pts_kernel(const float* __restrict__ points,
                                                        float* __restrict__ pts) {
    int i = blockIdx.x * 256 + threadIdx.x;   // over B*L*NPTS = 166400
    if (i >= BB * LL * NPTS) return;
    int n = i % NPTS;
    int bl = i / NPTS;
    if (n < NN) {
        const float* src = points + ((size_t)bl * NN + n) * 3;
        pts[(size_t)i * 3 + 0] = src[0];
        pts[(size_t)i * 3 + 1] = src[1];
        pts[(size_t)i * 3 + 2] = src[2];
    } else {
        int j = n - NN;
        int ix = j >> 4, iy = (j >> 2) & 3, iz = j & 3;
        pts[(size_t)i * 3 + 0] = -1.5f + (float)ix;
        pts[(size_t)i * 3 + 1] = -1.5f + (float)iy;
        pts[(size_t)i * 3 + 2] = -1.5f + (float)iz;
    }
}

// ---------------------------------------------------------------------------
// FPS (blocks 0..23, 256 thr = 4 waves) + wsplit for BOTH layer 0 (blocks
// 24..2071 -> buffer 0) and layer 1 (blocks 2072..4119 -> buffer 1): fps
// occupies only 24 CUs for ~170us, so both fills ride the idle capacity.
// ---------------------------------------------------------------------------
__global__ __launch_bounds__(256) void fps_ws_kernel(
    const float* __restrict__ pts, float* __restrict__ axyz,
    const float* __restrict__ qkvw, const float* __restrict__ projw,
    const float* __restrict__ ff1w, const float* __restrict__ ff2w,
    ushort_t* __restrict__ th, ushort_t* __restrict__ tl,
    const float* __restrict__ qkvw1, const float* __restrict__ projw1,
    const float* __restrict__ ff1w1, const float* __restrict__ ff2w1,
    ushort_t* __restrict__ th1, ushort_t* __restrict__ tl1) {
    __shared__ __align__(16) char smem[50048];
    int bid = blockIdx.x;
    int tid = threadIdx.x;
    if (bid >= 24) {
        int widx = bid - 24;
        if (widx < 2048)
            wsplit_tile(widx, tid, 256, qkvw, projw, ff1w, ff2w, th, tl,
                        (float(*)[33])smem);
        else
            wsplit_tile(widx - 2048, tid, 256, qkvw1, projw1, ff1w1, ff2w1,
                        th1, tl1, (float(*)[33])smem);
        return;
    }
    float* sx = (float*)smem;
    float* sy = sx + NPTS;
    float* sz = sy + NPTS;
    float* redv = sz + NPTS;          // [2][4]
    int* redi = (int*)(redv + 8);     // [2][4]

    int b = bid / 3, f = bid % 3;
    const float* P = pts + (size_t)(b * LL + 2 * f) * NPTS * 3;
    int lane = tid & 63, wid = tid >> 6;
    // thread t<64 owns 17 pts [17t..); t>=64 owns 16 starting 1088+16(t-64).
    int start = tid < 64 ? 17 * tid : 1088 + 16 * (tid - 64);
    float px[17], py[17], pz[17], dist[17];
#pragma unroll
    for (int j = 0; j < 16; j++) {
        int n = start + j;
        float gx = P[(size_t)n * 3 + 0];
        float gy = P[(size_t)n * 3 + 1];
        float gz = P[(size_t)n * 3 + 2];
        px[j] = gx; py[j] = gy; pz[j] = gz;
        sx[n] = gx; sy[n] = gy; sz[n] = gz;
        dist[j] = 1e10f;
    }
    if (tid < 64) {                   // wave-uniform (wave 0)
        int n = start + 16;
        float gx = P[(size_t)n * 3 + 0];
        float gy = P[(size_t)n * 3 + 1];
        float gz = P[(size_t)n * 3 + 2];
        px[16] = gx; py[16] = gy; pz[16] = gz;
        sx[n] = gx; sy[n] = gy; sz[n] = gz;
        dist[16] = 1e10f;
    } else {
        px[16] = 0.f; py[16] = 0.f; pz[16] = 0.f;
        dist[16] = -1.0f;
    }
    __syncthreads();
    float ax = sx[0], ay = sy[0], az = sz[0];
    float* out = axyz + (size_t)bid * MM * 3;
    for (int m = 0; m < MM; m++) {
        if (tid == 0) { out[m * 3 + 0] = ax; out[m * 3 + 1] = ay; out[m * 3 + 2] = az; }
        float bv = -1.0f;
        int bjn = start;
#pragma unroll
        for (int j = 0; j < 16; j++) {
            float d = sqdist_rn(px[j], py[j], pz[j], ax, ay, az);
            float dj = fminf(dist[j], d);
            dist[j] = dj;
            if (dj > bv) { bv = dj; bjn = start + j; }   // strict >: first j wins
        }
        if (tid < 64) {               // wave-uniform extra point
            float d = sqdist_rn(px[16], py[16], pz[16], ax, ay, az);
            float dj = fminf(dist[16], d);
            dist[16] = dj;
            if (dj > bv) { bv = dj; bjn = start + 16; }
        }
        float wmv = wave_max_bcast(bv);
        unsigned long long mk = __ballot(bv == wmv);
        int srcl = __ffsll(mk) - 1;   // lowest tied lane = smallest n
        int wn = __builtin_amdgcn_readlane(bjn, srcl);
        int par = (m & 1) * 4;        // ping-pong: iter m+1 writes other half
        if (lane == 0) { redv[par + wid] = wmv; redi[par + wid] = wn; }
        __syncthreads();
        float b0 = redv[par + 0], b1 = redv[par + 1];
        float b2 = redv[par + 2], b3 = redv[par + 3];
        int i0 = redi[par + 0], i1 = redi[par + 1];
        int i2 = redi[par + 2], i3 = redi[par + 3];
        float bb = b0; int bn = i0;                  // first-wins: wave order =
        if (b1 > bb) { bb = b1; bn = i1; }           // ascending n -> smallest n
        if (b2 > bb) { bb = b2; bn = i2; }
        if (b3 > bb) { bb = b3; bn = i3; }
        ax = sx[bn]; ay = sy[bn]; az = sz[bn];
    }
}

// ---------------------------------------------------------------------------
// Ball query + grouped conv + max over k + max over window + pos embedding.
// 4 anchors per 256-thr block (one wave each, per-wave LDS, no barriers).
// ---------------------------------------------------------------------------
__global__ __launch_bounds__(256) void group_conv_kernel(
    const float* __restrict__ pts, const float* __restrict__ axyz,
    const float* __restrict__ conv_d_w, const float* __restrict__ conv_f_w,
    const float* __restrict__ pos_w, const float* __restrict__ pos_b,
    float* __restrict__ x) {
    int wid = threadIdx.x >> 6;
    int gid = blockIdx.x * 4 + wid;       // b*780 + f*260 + m
    int b = gid / SSEQ;
    int rem = gid % SSEQ;
    int f = rem / MM;
    int lane = threadIdx.x & 63;
    const float* A = axyz + (size_t)gid * 3;
    float ax = A[0], ay = A[1], az = A[2];

    float cf0[8], cf1[8], cf2[8], cd0[8], cd1[8], cd2[8], cd3[8], fmx[8];
#pragma unroll
    for (int c = 0; c < 8; c++) {
        int d = lane + 64 * c;
        cf0[c] = conv_f_w[d * 3 + 0];
        cf1[c] = conv_f_w[d * 3 + 1];
        cf2[c] = conv_f_w[d * 3 + 2];
        cd0[c] = conv_d_w[d * 4 + 0];
        cd1[c] = conv_d_w[d * 4 + 1];
        cd2[c] = conv_d_w[d * 4 + 2];
        cd3[c] = conv_d_w[d * 4 + 3];
        fmx[c] = -INFINITY;
    }
    __shared__ int nbr[4][32];
    __shared__ float gxs[4][32], gys[4][32], gzs[4][32];
    const float R2 = 0.49000000953674316f;

    for (int wi = 0; wi < 3; wi++) {
        int l = 2 * f + wi - 1;
        l = l < 0 ? 0 : (l > 4 ? 4 : l);
        const float* P = pts + (size_t)(b * LL + l) * NPTS * 3;
        int cnt = 0;
        for (int base = 0; base < NPTS && cnt < 32; base += 64) {
            int n = base + lane;
            float d2 = sqdist_rn(P[(size_t)n * 3], P[(size_t)n * 3 + 1], P[(size_t)n * 3 + 2],
                                 ax, ay, az);
            bool hit = d2 < R2;
            unsigned long long mk = __ballot(hit);
            int rank = (int)__popcll(mk & (((unsigned long long)1 << lane) - 1ull));
            if (hit && (cnt + rank) < 32) nbr[wid][cnt + rank] = n;
            cnt += (int)__popcll(mk);
        }
        int eff = cnt < 32 ? cnt : 32;
        if (lane < 32) {
            int idx = (eff == 0) ? 0 : (lane < eff ? nbr[wid][lane] : nbr[wid][0]);
            gxs[wid][lane] = P[(size_t)idx * 3 + 0];
            gys[wid][lane] = P[(size_t)idx * 3 + 1];
            gzs[wid][lane] = P[(size_t)idx * 3 + 2];
        }
        float tf = (float)(wi - 1);
        for (int k = 0; k < 32; k++) {
            float gx = gxs[wid][k], gy = gys[wid][k], gz = gzs[wid][k];
            float dx = gx - ax, dy = gy - ay, dz = gz - az;
#pragma unroll
            for (int c = 0; c < 8; c++) {
                float v = gx * cf0[c] + gy * cf1[c] + gz * cf2[c] +
                          dx * cd0[c] + dy * cd1[c] + dz * cd2[c] + tf * cd3[c];
                fmx[c] = fmaxf(fmx[c], v);
            }
        }
    }
    float tcol = (float)(f + 1);
#pragma unroll
    for (int c = 0; c < 8; c++) {
        int d = lane + 64 * c;
        float pos = ax * pos_w[d * 4 + 0] + ay * pos_w[d * 4 + 1] +
                    az * pos_w[d * 4 + 2] + tcol * pos_w[d * 4 + 3] + pos_b[d];
        x[(size_t)gid * DIMC + d] = fmx[c] + pos;
    }
}

// ---------------------------------------------------------------------------
// LayerNorm over last dim 512; output written as bf16 hi/lo split (GEMM A).
// 4 rows per 256-thr block (one wave each, no cross-wave interaction).
// ---------------------------------------------------------------------------
__global__ __launch_bounds__(256) void ln_kernel(const float* __restrict__ x,
                                                 const float* __restrict__ g,
                                                 const float* __restrict__ b,
                                                 ushort_t* __restrict__ yh,
                                                 ushort_t* __restrict__ yl) {
    int r = blockIdx.x * 4 + (threadIdx.x >> 6);
    int lane = threadIdx.x & 63;
    const float* xr = x + (size_t)r * DIMC;
    float4 v0 = *(const float4*)(xr + lane * 8);
    float4 v1 = *(const float4*)(xr + lane * 8 + 4);
    float s = v0.x + v0.y + v0.z + v0.w + v1.x + v1.y + v1.z + v1.w;
    s = wave_sum_bcast(s);
    float mean = s * (1.0f / 512.0f);
    float dv[8];
    dv[0] = v0.x - mean; dv[1] = v0.y - mean; dv[2] = v0.z - mean; dv[3] = v0.w - mean;
    dv[4] = v1.x - mean; dv[5] = v1.y - mean; dv[6] = v1.z - mean; dv[7] = v1.w - mean;
    float sq = 0.f;
#pragma unroll
    for (int c = 0; c < 8; c++) sq += dv[c] * dv[c];
    sq = wave_sum_bcast(sq);
    float var = sq * (1.0f / 512.0f);
    float inv = 1.0f / sqrtf(var + 1e-5f);
    int d = lane * 8;
    ushort_t hs[8], ls[8];
#pragma unroll
    for (int c = 0; c < 8; c++) {
        float v = dv[c] * inv * g[d + c] + b[d + c];
        split2(v, hs[c], ls[c]);
    }
    uint4 hv, lv;
    hv.x = hs[0] | ((uint_t)hs[1] << 16); hv.y = hs[2] | ((uint_t)hs[3] << 16);
    hv.z = hs[4] | ((uint_t)hs[5] << 16); hv.w = hs[6] | ((uint_t)hs[7] << 16);
    lv.x = ls[0] | ((uint_t)ls[1] << 16); lv.y = ls[2] | ((uint_t)ls[3] << 16);
    lv.z = ls[4] | ((uint_t)ls[5] << 16); lv.w = ls[6] | ((uint_t)ls[7] << 16);
    *(uint4*)(yh + (size_t)r * DIMC + d) = hv;
    *(uint4*)(yl + (size_t)r * DIMC + d) = lv;
}

// ---------------------------------------------------------------------------
// bf16x3 MFMA GEMM (fp32 emulation): C = A @ W.
// Structure: stage -> barrier -> ds_read frags -> MFMA -> barrier; staging
// latency hidden by TLP.  Bijective XCD-aware block swizzle for L2 locality.
// EPI: 0 = fp32 C; 2 = bias+gelu -> split (Ch,Cl); 3 = bias+R -> C;
//      5 = qkv: Q/K cols -> split (Ch,Cl) stride 1024; V cols -> transposed
//          vT[(b*8+h)*64+d][key] split (Vh,Vl), key pitch VPITCH; V-writes
//          packed u64 (4 consecutive keys, never straddles a batch).
// ---------------------------------------------------------------------------
#define BK 32   // k per step (LDS row length in ushorts)

template <int BN, int EPI>
__global__ __launch_bounds__(256) void gemm_mfma(
    const ushort_t* __restrict__ Ahg, const ushort_t* __restrict__ Alg,
    const ushort_t* __restrict__ Bhg, const ushort_t* __restrict__ Blg,
    const float* __restrict__ bias, const float* __restrict__ R,
    float* __restrict__ C, ushort_t* __restrict__ Ch, ushort_t* __restrict__ Cl,
    ushort_t* __restrict__ Vh, ushort_t* __restrict__ Vl,
    int M, int N, int K) {
    const int WN = BN / 2, NT = WN / 16;
    __shared__ __align__(16) ushort_t Ah[128 * BK];
    __shared__ __align__(16) ushort_t Al[128 * BK];
    __shared__ __align__(16) ushort_t Bh[BN * BK];
    __shared__ __align__(16) ushort_t Bl[BN * BK];
    int tid = threadIdx.x;
    int lane = tid & 63, w = tid >> 6;
    int wm = w & 1, wn = w >> 1;
    int quad = lane >> 4, l15 = lane & 15;

    // bijective XCD swizzle (T1): each XCD gets a contiguous chunk of linear
    // block ids -> consecutive row-blocks share A panels in the XCD's L2.
    int nx = gridDim.x;
    int nwg = nx * gridDim.y;
    int lid = blockIdx.x + nx * blockIdx.y;
    int q = nwg >> 3, r = nwg & 7;
    int xcd = lid & 7, off = lid >> 3;
    int nid = (xcd < r ? xcd * (q + 1) : r * (q + 1) + (xcd - r) * q) + off;
    int m0 = (nid / nx) * 128, n0 = (nid % nx) * BN;

    // staging geometry: one gload16 stages a 16-row group; lane l -> row l>>2,
    // 16B chunk l&3 (linear dest). Source chunk pre-swizzled by (row>>1)&3.
    int sr = lane >> 2;
    int sc = lane & 3;
    int kq = ((sc ^ ((sr >> 1) & 3)) << 3);   // swizzled ushort k-offset [0,32)

    int aoff[2];
#pragma unroll
    for (int i = 0; i < 2; i++) {
        int g = w + 4 * i;
        int row = m0 + g * 16 + sr; if (row >= M) row = M - 1;
        aoff[i] = row * K + kq;
    }
    int boff[BN == 128 ? 2 : 1];
    if (BN == 128) {
#pragma unroll
        for (int i = 0; i < 2; i++) {
            int g = w + 4 * i;
            boff[i] = (n0 + g * 16 + sr) * K + kq;
        }
    } else {
        boff[0] = (n0 + w * 16 + sr) * K + kq;
    }

    fx4 acc[4][NT];
#pragma unroll
    for (int mi = 0; mi < 4; mi++)
#pragma unroll
        for (int nj = 0; nj < NT; nj++) acc[mi][nj] = (fx4){0.f, 0.f, 0.f, 0.f};

    // fragment-read addresses (swizzled 16B chunk; same XOR as the source)
    int rsw = (l15 >> 1) & 3;
    int aro = (64 * wm + l15) * BK + ((quad ^ rsw) << 3);
    int bro = (WN * wn + l15) * BK + ((quad ^ rsw) << 3);

    for (int k0 = 0; k0 < K; k0 += BK) {
#pragma unroll
        for (int i = 0; i < 2; i++) {
            int g = w + 4 * i;
            gload16(Ahg + aoff[i] + k0, &Ah[g * 16 * BK]);
            gload16(Alg + aoff[i] + k0, &Al[g * 16 * BK]);
        }
        if (BN == 128) {
#pragma unroll
            for (int i = 0; i < 2; i++) {
                int g = w + 4 * i;
                gload16(Bhg + boff[i] + k0, &Bh[g * 16 * BK]);
                gload16(Blg + boff[i] + k0, &Bl[g * 16 * BK]);
            }
        } else {
            gload16(Bhg + boff[0] + k0, &Bh[w * 16 * BK]);
            gload16(Blg + boff[0] + k0, &Bl[w * 16 * BK]);
        }
        __syncthreads();   // drains vmcnt(0): staged data visible

        s16x8 bf[NT][2];
#pragma unroll
        for (int nj = 0; nj < NT; nj++) {
            bf[nj][0] = *(const s16x8*)&Bh[bro + 16 * nj * BK];
            bf[nj][1] = *(const s16x8*)&Bl[bro + 16 * nj * BK];
        }
#pragma unroll
        for (int mi = 0; mi < 4; mi++) {
            s16x8 aH = *(const s16x8*)&Ah[aro + 16 * mi * BK];
            s16x8 aL = *(const s16x8*)&Al[aro + 16 * mi * BK];
#pragma unroll
            for (int nj = 0; nj < NT; nj++) {
                acc[mi][nj] = __builtin_amdgcn_mfma_f32_16x16x32_bf16(aH, bf[nj][0], acc[mi][nj], 0, 0, 0);
                acc[mi][nj] = __builtin_amdgcn_mfma_f32_16x16x32_bf16(aH, bf[nj][1], acc[mi][nj], 0, 0, 0);
                acc[mi][nj] = __builtin_amdgcn_mfma_f32_16x16x32_bf16(aL, bf[nj][0], acc[mi][nj], 0, 0, 0);
            }
        }
        __syncthreads();   // all reads done before next step's DMA overwrites
    }
    if (EPI == 5) {
#pragma unroll
        for (int mi = 0; mi < 4; mi++) {
#pragma unroll
            for (int nj = 0; nj < NT; nj++) {
                int col = n0 + WN * wn + 16 * nj + l15;
                int row0 = m0 + 64 * wm + 16 * mi + quad * 4;
                if (row0 < M) {       // rows row0..row0+3 all valid (M%4==0)
                    if (col < 1024) {
#pragma unroll
                        for (int r2 = 0; r2 < 4; r2++) {
                            ushort_t h, l;
                            split2(acc[mi][nj][r2], h, l);
                            Ch[(size_t)(row0 + r2) * 1024 + col] = h;
                            Cl[(size_t)(row0 + r2) * 1024 + col] = l;
                        }
                    } else {
                        int bb = row0 / SSEQ, key0 = row0 % SSEQ;
                        int hh = (col - 1024) >> 6, dd = (col - 1024) & 63;
                        size_t vo = ((size_t)((bb * 8 + hh) * 64 + dd)) * VPITCH + key0;
                        u64_t ph = 0, pl = 0;
#pragma unroll
                        for (int r2 = 0; r2 < 4; r2++) {
                            ushort_t h, l;
                            split2(acc[mi][nj][r2], h, l);
                            ph |= (u64_t)h << (16 * r2);
                            pl |= (u64_t)l << (16 * r2);
                        }
                        *(u64_t*)(Vh + vo) = ph;
                        *(u64_t*)(Vl + vo) = pl;
                    }
                }
            }
        }
    } else {
#pragma unroll
        for (int mi = 0; mi < 4; mi++) {
#pragma unroll
            for (int r2 = 0; r2 < 4; r2++) {
                int row = m0 + 64 * wm + 16 * mi + quad * 4 + r2;
                if (row < M) {
#pragma unroll
                    for (int nj = 0; nj < NT; nj++) {
                        int col = n0 + WN * wn + 16 * nj + l15;
                        float v = acc[mi][nj][r2];
                        if (EPI == 0) {
                            C[(size_t)row * N + col] = v;
                        } else if (EPI == 3) {
                            C[(size_t)row * N + col] = v + bias[col] + R[(size_t)row * N + col];
                        } else if (EPI == 2) {
                            float gv = gelu_exact(v + bias[col]);
                            ushort_t h, l;
                            split2(gv, h, l);
                            Ch[(size_t)row * N + col] = h;
                            Cl[(size_t)row * N + col] = l;
                        }
                    }
                }
            }
        }
    }
}

// ---------------------------------------------------------------------------
// MFMA flash attention (lid < 448) + next-layer wsplit (lid >= 448, only for
// layers 1..3 -> fills buffer (l+1)&1; layers 0 and 4 launch attn-only).
// QBLK=128, 8 waves; Q in registers; K/V via global_load_lds + both-sides
// XOR swizzle; XCD grouping (7 qt-blocks of a (b,h) share lid%8); swapped
// QK^T with packed ds_write_b64 P-store; s_setprio around MFMA clusters.
// ---------------------------------------------------------------------------
#define KP2 64     // K/V LDS pitch (ushorts): linear rows for gload16
#define PP 72      // P LDS pitch (ushorts)
#define NATTN 448  // 7 qt * 64 bh

__global__ __launch_bounds__(512, 4) void attn_mfma_kernel(
    const ushort_t* __restrict__ qkh, const ushort_t* __restrict__ qkl,
    const ushort_t* __restrict__ vth, const ushort_t* __restrict__ vtl,
    ushort_t* __restrict__ oh, ushort_t* __restrict__ ol,
    const float* __restrict__ nqkvw, const float* __restrict__ nprojw,
    const float* __restrict__ nff1w, const float* __restrict__ nff2w,
    ushort_t* __restrict__ nth, ushort_t* __restrict__ ntl) {
    __shared__ __align__(16) char smem[69632];
    int lid = blockIdx.x;
    if (lid >= NATTN) {
        int widx = lid - NATTN;
        wsplit_tile(widx, threadIdx.x, 512, nqkvw, nprojw, nff1w, nff2w,
                    nth, ntl, (float(*)[33])smem);
        return;
    }
    // XCD-grouped decode: xcd residue = lid&7; idx = lid>>3 in [0,56):
    // qt = idx%7, bh = (lid&7)*8 + idx/7  -> all qt of a bh share lid%8.
    int xcd = lid & 7, idx = lid >> 3;
    int qt = idx % 7;
    int bh = xcd * 8 + idx / 7;
    int b = bh >> 3, h = bh & 7;

    ushort_t* Kh  = (ushort_t*)smem;          // 64 x KP2 each
    ushort_t* Kl  = Kh + 64 * KP2;
    ushort_t* Vth = Kl + 64 * KP2;
    ushort_t* Vtl = Vth + 64 * KP2;
    ushort_t* Ph  = Vtl + 64 * KP2;           // 128 x PP each
    ushort_t* Pl  = Ph + 128 * PP;

    int tid = threadIdx.x;
    int lane = tid & 63, w = tid >> 6;        // w in 0..7
    int quad = lane >> 4, l15 = lane & 15;

    int q0 = qt * 128;
    int nq = SSEQ - q0; if (nq > 128) nq = 128;

    // Q fragments in registers: wave w's rows 16w..16w+15, both 32-k chunks.
    s16x8 qfh[2], qfl[2];
    {
        int row = 16 * w + l15;
        int gq = q0 + (row < nq ? row : nq - 1);
        size_t go = (size_t)(b * SSEQ + gq) * 1024 + h * 64;
#pragma unroll
        for (int ks = 0; ks < 2; ks++) {
            qfh[ks] = *(const s16x8*)(qkh + go + 32 * ks + quad * 8);
            qfl[ks] = *(const s16x8*)(qkl + go + 32 * ks + quad * 8);
        }
    }

    fx4 accO[4];
#pragma unroll
    for (int dj = 0; dj < 4; dj++) accO[dj] = (fx4){0.f, 0.f, 0.f, 0.f};
    fx4 accL = (fx4){0.f, 0.f, 0.f, 0.f};

    s16x8 ones;
#pragma unroll
    for (int j = 0; j < 8; j++) ones[j] = (short)16256;   // bf16 1.0

    // staging geometry: one gload16 group = 8 rows x 8 chunks = 1KB, wave-
    // uniform dest base; lane -> row lane>>3, chunk lane&7, source chunk
    // pre-swizzled by row&7 (read side applies the same XOR).
    int sr8 = lane >> 3;
    int csw = (lane & 7) ^ sr8;

    // fragment chunk offsets: global chunk g = 4*ks+quad at LDS row r lives
    // at chunk g^(r&7); r&7 == l15&7 for all fragment rows used below.
    int r7 = l15 & 7;
    int c0 = (quad ^ r7) * 8;          // ks = 0 (ushort offset)
    int c1 = ((quad ^ r7) ^ 4) * 8;    // ks = 1

    for (int kt = 0; kt < 13; kt++) {
        int k0 = kt * 64;
        int nk = SSEQ - k0; if (nk > 64) nk = 64;
        __syncthreads();   // prior QK/PV reads done before DMA overwrite
        {
            int row = w * 8 + sr8;     // 8 waves x 8 rows = 64 rows
            int gk = k0 + (row < nk ? row : nk - 1);
            size_t go = (size_t)(b * SSEQ + gk) * 1024 + h * 64 + 512 + csw * 8;
            gload16(qkh + go, Kh + w * 512);
            gload16(qkl + go, Kl + w * 512);
            size_t vo = ((size_t)(bh * 64 + row)) * VPITCH + k0 + csw * 8;
            gload16(vth + vo, Vth + w * 512);
            gload16(vtl + vo, Vtl + w * 512);
        }
        __syncthreads();   // vmcnt drained: tiles visible

        // S^T tile via swapped operands: A = K rows (keys), B = Q regs.
        // accS[nj][r] = S[q = 16w+l15][key = 16nj + quad*4 + r].
        fx4 accS[4];
#pragma unroll
        for (int nj = 0; nj < 4; nj++) accS[nj] = (fx4){0.f, 0.f, 0.f, 0.f};
        __builtin_amdgcn_s_setprio(1);
#pragma unroll
        for (int ks = 0; ks < 2; ks++) {
            int ca = ks ? c1 : c0;
            s16x8 bQh = qfh[ks];
            s16x8 bQl = qfl[ks];
#pragma unroll
            for (int nj = 0; nj < 4; nj++) {
                s16x8 aKh = *(const s16x8*)&Kh[(16 * nj + l15) * KP2 + ca];
                s16x8 aKl = *(const s16x8*)&Kl[(16 * nj + l15) * KP2 + ca];
                accS[nj] = __builtin_amdgcn_mfma_f32_16x16x32_bf16(aKh, bQh, accS[nj], 0, 0, 0);
                accS[nj] = __builtin_amdgcn_mfma_f32_16x16x32_bf16(aKl, bQh, accS[nj], 0, 0, 0);
                accS[nj] = __builtin_amdgcn_mfma_f32_16x16x32_bf16(aKh, bQl, accS[nj], 0, 0, 0);
            }
        }
        __builtin_amdgcn_s_setprio(0);
        // P = exp(S * scale): lane owns q-row 16w+l15, 4 consecutive keys per
        // nj -> pack hi/lo into u64 and store with ds_write_b64.
        {
            int qrow = 16 * w + l15;
#pragma unroll
            for (int nj = 0; nj < 4; nj++) {
                int kbase = 16 * nj + quad * 4;
                u64_t ph = 0, pl = 0;
#pragma unroll
                for (int r = 0; r < 4; r++) {
                    float s = accS[nj][r] * 0.125f;
                    float p = (kbase + r < nk) ? __expf(s) : 0.f;
                    ushort_t hh, ll;
                    split2(p, hh, ll);
                    ph |= (u64_t)hh << (16 * r);
                    pl |= (u64_t)ll << (16 * r);
                }
                *(u64_t*)&Ph[qrow * PP + kbase] = ph;
                *(u64_t*)&Pl[qrow * PP + kbase] = pl;
            }
        }
        // PV (x3) + l-sum (ones-B); wave-local, in-order DS => no barrier
        __builtin_amdgcn_s_setprio(1);
#pragma unroll
        for (int ks = 0; ks < 2; ks++) {
            int ca = ks ? c1 : c0;
            s16x8 aPh = *(const s16x8*)&Ph[(16 * w + l15) * PP + 32 * ks + quad * 8];
            s16x8 aPl = *(const s16x8*)&Pl[(16 * w + l15) * PP + 32 * ks + quad * 8];
            accL = __builtin_amdgcn_mfma_f32_16x16x32_bf16(aPh, ones, accL, 0, 0, 0);
            accL = __builtin_amdgcn_mfma_f32_16x16x32_bf16(aPl, ones, accL, 0, 0, 0);
#pragma unroll
            for (int dj = 0; dj < 4; dj++) {
                s16x8 bVh = *(const s16x8*)&Vth[(16 * dj + l15) * KP2 + ca];
                s16x8 bVl = *(const s16x8*)&Vtl[(16 * dj + l15) * KP2 + ca];
                accO[dj] = __builtin_amdgcn_mfma_f32_16x16x32_bf16(aPh, bVh, accO[dj], 0, 0, 0);
                accO[dj] = __builtin_amdgcn_mfma_f32_16x16x32_bf16(aPh, bVl, accO[dj], 0, 0, 0);
                accO[dj] = __builtin_amdgcn_mfma_f32_16x16x32_bf16(aPl, bVh, accO[dj], 0, 0, 0);
            }
        }
        __builtin_amdgcn_s_setprio(0);
    }
    // store O / l ; rows of accL align with rows of accO (C-layout)
#pragma unroll
    for (int r = 0; r < 4; r++) {
        int lq = 16 * w + quad * 4 + r;
        if (lq < nq) {
            float inv = 1.0f / accL[r];
            size_t base = (size_t)(b * SSEQ + q0 + lq) * DIMC + h * 64 + l15;
#pragma unroll
            for (int dj = 0; dj < 4; dj++) {
                ushort_t hh, ll;
                split2(accO[dj][r] * inv, hh, ll);
                oh[base + 16 * dj] = hh;
                ol[base + 16 * dj] = ll;
            }
        }
    }
}

// ---------------------------------------------------------------------------
// Head: two-stage max-pool (104 blocks -> parallelism) + LN, then head GEMVs.
// (Round-10's single-kernel pool fusion cut pool parallelism 13x -> reverted.)
// ---------------------------------------------------------------------------
__global__ __launch_bounds__(512) void pool_max_kernel(const float* __restrict__ x,
                                                       float* __restrict__ partial) {
    int c = blockIdx.x;        // 0..12 (chunks of 60 rows)
    int bb = blockIdx.y;
    int d = threadIdx.x;
    const float* xb = x + ((size_t)(bb * SSEQ + c * 60)) * DIMC + d;
    float m = -INFINITY;
#pragma unroll 4
    for (int s = 0; s < 60; s++) m = fmaxf(m, xb[(size_t)s * DIMC]);
    partial[((size_t)bb * 13 + c) * DIMC + d] = m;
}

__global__ __launch_bounds__(512) void pool_ln_kernel(const float* __restrict__ partial,
                                                      const float* __restrict__ g,
                                                      const float* __restrict__ b,
                                                      float* __restrict__ out) {
    int bb = blockIdx.x;
    int d = threadIdx.x;
    const float* pb = partial + (size_t)bb * 13 * DIMC + d;
    float m = -INFINITY;
#pragma unroll
    for (int c = 0; c < 13; c++) m = fmaxf(m, pb[(size_t)c * DIMC]);
    __shared__ float col[512];
    __shared__ float red[512];
    col[d] = m;
    red[d] = m;
    __syncthreads();
    for (int s = 256; s > 0; s >>= 1) {
        if (d < s) red[d] += red[d + s];
        __syncthreads();
    }
    float mean = red[0] * (1.0f / 512.0f);
    __syncthreads();
    float dv = col[d] - mean;
    red[d] = dv * dv;
    __syncthreads();
    for (int s = 256; s > 0; s >>= 1) {
        if (d < s) red[d] += red[d + s];
        __syncthreads();
    }
    float var = red[0] * (1.0f / 512.0f);
    float inv = 1.0f / sqrtf(var + 1e-5f);
    out[(size_t)bb * DIMC + d] = dv * inv * g[d] + b[d];
}

__global__ __launch_bounds__(256) void head1_kernel(const float* __restrict__ in,
                                                    const float* __restrict__ W,
                                                    const float* __restrict__ bias,
                                                    float* __restrict__ out) {
    int g = blockIdx.x, bb = blockIdx.y;
    int tid = threadIdx.x;
    int c = tid & 63, ks = tid >> 6;
    int col = g * 64 + c;
    __shared__ float xr[512];
    xr[tid] = in[(size_t)bb * 512 + tid];
    xr[tid + 256] = in[(size_t)bb * 512 + tid + 256];
    __syncthreads();
    float acc = 0.f;
    const float* Wc = W + col;
    for (int k = ks * 128; k < ks * 128 + 128; k++)
        acc += xr[k] * Wc[(size_t)k * MLPD];
    __shared__ float red[256];
    red[tid] = acc;
    __syncthreads();
    if (ks == 0) {
        float v = red[c] + red[c + 64] + red[c + 128] + red[c + 192] + bias[col];
        out[(size_t)bb * MLPD + col] = gelu_exact(v);
    }
}

// head2 + softmax-anchor fused: grid (17, BB) == smax's 136 groups; the
// ks==0 reduction lanes are exactly wave 0's 64 lanes -> run the wave-level
// softmax + anchor expectation in-place (identical value sequence to the
// former smax_anchor_kernel) and write the final output directly.
__global__ __launch_bounds__(256) void head2_kernel(const float* __restrict__ in,
                                                    const float* __restrict__ W,
                                                    const float* __restrict__ bias,
                                                    float* __restrict__ out) {
    int g = blockIdx.x, bb = blockIdx.y;
    int tid = threadIdx.x;
    int c = tid & 63, ks = tid >> 6;
    int col = g * 64 + c;
    __shared__ float xr[1024];
    xr[tid] = in[(size_t)bb * 1024 + tid];
    xr[tid + 256] = in[(size_t)bb * 1024 + tid + 256];
    xr[tid + 512] = in[(size_t)bb * 1024 + tid + 512];
    xr[tid + 768] = in[(size_t)bb * 1024 + tid + 768];
    __syncthreads();
    float acc = 0.f;
    const float* Wc = W + col;
    for (int k = ks * 256; k < ks * 256 + 256; k++)
        acc += xr[k] * Wc[(size_t)k * OUTD];
    __shared__ float red[256];
    red[tid] = acc;
    __syncthreads();
    if (ks == 0) {   // all 64 lanes of wave 0: full wave active for DPP ops
        float v = red[c] + red[c + 64] + red[c + 128] + red[c + 192] + bias[col];
        float mx = wave_max_bcast(v);
        float p = expf(v - mx);
        float sum = wave_sum_bcast(p);
        int ix = c >> 4, iy = (c >> 2) & 3, iz = c & 3;
        float sx = wave_sum_bcast(p * (-1.5f + (float)ix));
        float sy = wave_sum_bcast(p * (-1.5f + (float)iy));
        float sz = wave_sum_bcast(p * (-1.5f + (float)iz));
        if (c == 0) {
            float* o = out + ((size_t)bb * 17 + g) * 3;
            o[0] = sx / sum;
            o[1] = sy / sum;
            o[2] = sz / sum;
        }
    }
}

// ---------------------------------------------------------------------------
extern "C" void kernel_launch(void* const* d_in, const int* in_sizes, int n_in,
                              void* d_out, int out_size, void* d_ws, size_t ws_size,
                              hipStream_t stream) {
    const float* points     = (const float*)d_in[0];
    const float* conv_d_w   = (const float*)d_in[1];
    const float* conv_f_w   = (const float*)d_in[2];
    const float* pos_w      = (const float*)d_in[3];
    const float* pos_b      = (const float*)d_in[4];
    const float* ln1_g      = (const float*)d_in[5];
    const float* ln1_b      = (const float*)d_in[6];
    const float* qkv_w      = (const float*)d_in[7];
    const float* attn_out_w = (const float*)d_in[8];
    const float* attn_out_b = (const float*)d_in[9];
    const float* ln2_g      = (const float*)d_in[10];
    const float* ln2_b      = (const float*)d_in[11];
    const float* ff1_w      = (const float*)d_in[12];
    const float* ff1_b      = (const float*)d_in[13];
    const float* ff2_w      = (const float*)d_in[14];
    const float* ff2_b      = (const float*)d_in[15];
    const float* head_ln_g  = (const float*)d_in[16];
    const float* head_ln_b  = (const float*)d_in[17];
    const float* head1_w    = (const float*)d_in[18];
    const float* head1_b    = (const float*)d_in[19];
    const float* head2_w    = (const float*)d_in[20];
    const float* head2_b    = (const float*)d_in[21];

    // fp32 region
    float* ws = (float*)d_ws;
    float* pts    = ws;                    //   499,200 f
    float* axyz   = pts + 499200;          //    18,720 f
    float* xbuf   = axyz + 18720;          // 3,194,880 f
    float* qkvreg = xbuf + 3194880;        // 9,601,024 f (qk + vT, hi/lo)
    float* pooled = qkvreg + 9601024;      //     4,096 f
    float* h1     = pooled + 4096;         //     8,192 f
    float* h2     = h1 + 8192;             //     8,704 f (unused after fusion)
    float* fend   = h2 + 8704;
    // qk (stride 1024) + vT hi/lo inside qkvreg
    ushort_t* qkh = (ushort_t*)qkvreg;             // 6,389,760 us
    ushort_t* qkl = qkh + 6389760;                 // 6,389,760 us
    ushort_t* vth = qkl + 6389760;                 // 3,211,264 us (8*8*64*784)
    ushort_t* vtl = vth + 3211264;                 // 3,211,264 us
    // bf16 hi/lo region (ushort)
    ushort_t* us   = (ushort_t*)fend;
    ushort_t* xnh  = us;                   // 3,194,880 us
    ushort_t* xnl  = xnh + 3194880;
    ushort_t* atth = xnl + 3194880;
    ushort_t* attl = atth + 3194880;
    ushort_t* ffhh = attl + 3194880;       // 6,389,760 us
    ushort_t* ffhl = ffhh + 6389760;
    ushort_t* wbh  = ffhl + 6389760;       // 2 x WBUFSZ (ping-pong weights, hi)
    ushort_t* wbl  = wbh + 2 * WBUFSZ;     // 2 x WBUFSZ (lo)
    float* ppart = qkvreg;                 // alias: qkv dead after last layer

    build_pts_kernel<<<650, 256, 0, stream>>>(points, pts);
    // fps + wsplit for layer 0 (buf0) AND layer 1 (buf1): both ride the
    // ~230 idle CUs during fps's 170us serial phase.
    fps_ws_kernel<<<24 + 4096, 256, 0, stream>>>(
        pts, axyz, qkv_w, attn_out_w, ff1_w, ff2_w, wbh, wbl,
        qkv_w + (size_t)1 * 512 * 1536, attn_out_w + (size_t)1 * 512 * 512,
        ff1_w + (size_t)1 * 512 * 1024, ff2_w + (size_t)1 * 1024 * 512,
        wbh + WBUFSZ, wbl + WBUFSZ);
    group_conv_kernel<<<NROWS / 4, 256, 0, stream>>>(pts, axyz, conv_d_w, conv_f_w,
                                                     pos_w, pos_b, xbuf);
    const int MB = (NROWS + 127) / 128;    // 49 row-blocks
    for (int l = 0; l < 5; l++) {
        ushort_t* wth = wbh + (size_t)(l & 1) * WBUFSZ;
        ushort_t* wtl = wbl + (size_t)(l & 1) * WBUFSZ;
        ushort_t* nth = wbh + (size_t)((l + 1) & 1) * WBUFSZ;
        ushort_t* ntl = wbl + (size_t)((l + 1) & 1) * WBUFSZ;
        int ln2off = l * 512;
        ln_kernel<<<NROWS / 4, 256, 0, stream>>>(xbuf, ln1_g + ln2off, ln1_b + ln2off, xnh, xnl);
        gemm_mfma<128, 5><<<dim3(1536 / 128, MB), 256, 0, stream>>>(
            xnh, xnl, wth, wtl, nullptr, nullptr, nullptr, qkh, qkl, vth, vtl,
            NROWS, 1536, 512);
        // attn; layers 1..3 also wsplit layer l+1 into buffer (l+1)&1.
        bool dofill = (l >= 1 && l < 4);
        int lnx = l + 1;
        attn_mfma_kernel<<<dim3(dofill ? NATTN + 2048 : NATTN), 512, 0, stream>>>(
            qkh, qkl, vth, vtl, atth, attl,
            dofill ? qkv_w + (size_t)lnx * 512 * 1536 : nullptr,
            dofill ? attn_out_w + (size_t)lnx * 512 * 512 : nullptr,
            dofill ? ff1_w + (size_t)lnx * 512 * 1024 : nullptr,
            dofill ? ff2_w + (size_t)lnx * 1024 * 512 : nullptr,
            nth, ntl);
        gemm_mfma<64, 3><<<dim3(512 / 64, MB), 256, 0, stream>>>(
            atth, attl, wth + 786432, wtl + 786432, attn_out_b + ln2off, xbuf,
            xbuf, nullptr, nullptr, nullptr, nullptr, NROWS, 512, 512);
        ln_kernel<<<NROWS / 4, 256, 0, stream>>>(xbuf, ln2_g + ln2off, ln2_b + ln2off, xnh, xnl);
        gemm_mfma<128, 2><<<dim3(1024 / 128, MB), 256, 0, stream>>>(
            xnh, xnl, wth + 1048576, wtl + 1048576, ff1_b + l * 1024, nullptr,
            nullptr, ffhh, ffhl, nullptr, nullptr, NROWS, 1024, 512);
        gemm_mfma<64, 3><<<dim3(512 / 64, MB), 256, 0, stream>>>(
            ffhh, ffhl, wth + 1572864, wtl + 1572864, ff2_b + ln2off, xbuf,
            xbuf, nullptr, nullptr, nullptr, nullptr, NROWS, 512, 1024);
    }
    pool_max_kernel<<<dim3(13, BB), 512, 0, stream>>>(xbuf, ppart);
    pool_ln_kernel<<<BB, 512, 0, stream>>>(ppart, head_ln_g, head_ln_b, pooled);
    head1_kernel<<<dim3(16, BB), 256, 0, stream>>>(pooled, head1_w, head1_b, h1);
    head2_kernel<<<dim3(17, BB), 256, 0, stream>>>(h1, head2_w, head2_b, (float*)d_out);
}